// Round 2
// baseline (1308.822 us; speedup 1.0000x reference)
//
#include <hip/hip_runtime.h>
#include <math.h>

// N=50000, E=400000, F_IN=128, HID=64, OUT=40, H=4
#define SLOPE 0.2f

// ---------------- bf16 helpers (raw ushort storage) ----------------
typedef unsigned short bf16_t;
__device__ __forceinline__ float ld_elem(const float* p, size_t i) { return p[i]; }
__device__ __forceinline__ float ld_elem(const bf16_t* p, size_t i) {
    return __uint_as_float((unsigned)p[i] << 16);
}
__device__ __forceinline__ void st_elem(float* p, size_t i, float v) { p[i] = v; }
__device__ __forceinline__ void st_elem(bf16_t* p, size_t i, float v) {
    unsigned u = __float_as_uint(v);
    unsigned r = (u + 0x7FFFu + ((u >> 16) & 1u)) >> 16;  // round-to-nearest-even
    p[i] = (bf16_t)r;
}

// ---------------- CSR build ----------------

__global__ void hist_dst(const int* __restrict__ dst, int E, int* __restrict__ deg) {
    int e = blockIdx.x * 256 + threadIdx.x;
    if (e < E) atomicAdd(&deg[dst[e]], 1);
}

__global__ void deg_chunk_sum(const int* __restrict__ deg, int n, int* __restrict__ chunk_sums) {
    __shared__ int sm[256];
    int base = blockIdx.x * 1024;
    int s = 0;
    for (int i = threadIdx.x; i < 1024; i += 256) {
        int idx = base + i;
        if (idx < n) s += deg[idx];
    }
    sm[threadIdx.x] = s;
    __syncthreads();
    for (int off = 128; off > 0; off >>= 1) {
        if (threadIdx.x < off) sm[threadIdx.x] += sm[threadIdx.x + off];
        __syncthreads();
    }
    if (threadIdx.x == 0) chunk_sums[blockIdx.x] = sm[0];
}

__global__ void scan_chunk_sums(int* __restrict__ chunk_sums, int nchunks) {
    __shared__ int sm[256];
    int t = threadIdx.x;
    if (t < nchunks) sm[t] = chunk_sums[t];
    __syncthreads();
    if (t == 0) {
        int run = 0;
        for (int i = 0; i < nchunks; i++) { int v = sm[i]; sm[i] = run; run += v; }
    }
    __syncthreads();
    if (t < nchunks) chunk_sums[t] = sm[t];
}

__global__ void scan_write(const int* __restrict__ deg, int n,
                           const int* __restrict__ chunk_sums,
                           int* __restrict__ row_start, int Etot) {
    int base = blockIdx.x * 1024;
    int t = threadIdx.x;
    int v[4];
    int tsum = 0;
#pragma unroll
    for (int j = 0; j < 4; j++) {
        int idx = base + t * 4 + j;
        v[j] = (idx < n) ? deg[idx] : 0;
        tsum += v[j];
    }
    __shared__ int sm[256];
    sm[t] = tsum;
    __syncthreads();
    for (int off = 1; off < 256; off <<= 1) {
        int x = (t >= off) ? sm[t - off] : 0;
        __syncthreads();
        sm[t] += x;
        __syncthreads();
    }
    int excl = sm[t] - tsum + chunk_sums[blockIdx.x];
#pragma unroll
    for (int j = 0; j < 4; j++) {
        int idx = base + t * 4 + j;
        if (idx < n) row_start[idx] = excl;
        excl += v[j];
    }
    if (blockIdx.x == 0 && t == 0) row_start[n] = Etot;
}

// stores SRC NODE ID (not edge id) grouped by dst
__global__ void scatter_edges(const int* __restrict__ dst, const int* __restrict__ src, int E,
                              const int* __restrict__ row_start,
                              int* __restrict__ fill, int* __restrict__ src_sorted) {
    int e = blockIdx.x * 256 + threadIdx.x;
    if (e < E) {
        int d_ = dst[e];
        int pos = row_start[d_] + atomicAdd(&fill[d_], 1);
        src_sorted[pos] = src[e];
    }
}

// fold w_res2 [256,160] -> w_eff [256,40] (mean over 4 head blocks), same for bias
__global__ void build_weff(const float* __restrict__ w_res2, const float* __restrict__ b_res2,
                           float* __restrict__ w_eff, float* __restrict__ b_eff) {
    int i = blockIdx.x * 256 + threadIdx.x;
    if (i < 256 * 40) {
        int k = i / 40, d = i % 40;
        const float* row = w_res2 + (size_t)k * 160;
        w_eff[i] = 0.25f * (row[d] + row[40 + d] + row[80 + d] + row[120 + d]);
    }
    if (i < 40)
        b_eff[i] = 0.25f * (b_res2[i] + b_res2[40 + i] + b_res2[80 + i] + b_res2[120 + i]);
}

// ---------------- tiled GEMM: C[M,Nc] (+)= A[M,K]@W[K,Nc] + bias ----------------
// BM=BN=64, BK=16, 256 threads, 4x4 micro-tile.

template <typename Ta, typename Tc, bool ACCUM>
__global__ __launch_bounds__(256) void gemm_bias(
    const Ta* __restrict__ A, const float* __restrict__ W,
    const float* __restrict__ bias, Tc* __restrict__ C,
    int M, int K, int Nc)
{
    __shared__ float As[16][72];
    __shared__ float Bs[16][72];
    int tid = threadIdx.x;
    int tx = tid & 15;
    int ty = tid >> 4;
    int m0 = blockIdx.y * 64;
    int n0 = blockIdx.x * 64;
    float acc[4][4] = {};

    for (int k0 = 0; k0 < K; k0 += 16) {
#pragma unroll
        for (int i = 0; i < 4; i++) {
            int idx = tid + i * 256;
            int r = idx >> 4;
            int c = idx & 15;
            int gm = m0 + r;
            As[c][r] = (gm < M) ? ld_elem(A, (size_t)gm * K + k0 + c) : 0.f;
        }
#pragma unroll
        for (int i = 0; i < 4; i++) {
            int idx = tid + i * 256;
            int r = idx >> 6;
            int c = idx & 63;
            int gn = n0 + c;
            Bs[r][c] = (gn < Nc) ? W[(size_t)(k0 + r) * Nc + gn] : 0.f;
        }
        __syncthreads();
#pragma unroll
        for (int k = 0; k < 16; k++) {
            float4 av = *(const float4*)&As[k][ty * 4];
            float4 bv = *(const float4*)&Bs[k][tx * 4];
            float a[4] = {av.x, av.y, av.z, av.w};
            float b[4] = {bv.x, bv.y, bv.z, bv.w};
#pragma unroll
            for (int i = 0; i < 4; i++)
#pragma unroll
                for (int j = 0; j < 4; j++)
                    acc[i][j] += a[i] * b[j];
        }
        __syncthreads();
    }
#pragma unroll
    for (int i = 0; i < 4; i++) {
        int gm = m0 + ty * 4 + i;
        if (gm >= M) continue;
#pragma unroll
        for (int j = 0; j < 4; j++) {
            int gn = n0 + tx * 4 + j;
            if (gn < Nc) {
                size_t ci = (size_t)gm * Nc + gn;
                float v = acc[i][j] + bias[gn];
                if (ACCUM) v += ld_elem(C, ci);
                st_elem(C, ci, v);
            }
        }
    }
}

// ---------------- GATv2 aggregation: one block per dst node ----------------
// S = staging dtype of hs/hd; P = dtype of non-final output (and in-place res).
// FINAL: write f32 head-mean to out_final (residual handled by later GEMM-accum).
// RES_INPLACE: out[n,f] = agg + out[n,f] (identity residual, same-thread RMW).

template <int D, bool FINAL, bool RES_INPLACE, typename S, typename P>
__global__ __launch_bounds__(256) void gat_aggregate(
    const S* __restrict__ hs, const S* __restrict__ hd,
    const float* __restrict__ attn,
    const int* __restrict__ row_start, const int* __restrict__ src_sorted,
    P* __restrict__ out, float* __restrict__ out_final)
{
    const int HD = 4 * D;
    int n = blockIdx.x;
    int t = threadIdx.x;
    int h = t >> 6;
    int d = t & 63;
    bool active = (d < D);
    int fidx = h * D + d;

    float hd_val = 0.f, attn_val = 0.f;
    if (active) {
        hd_val = ld_elem(hd, (size_t)n * HD + fidx);
        attn_val = attn[fidx];
    }
    int s = row_start[n];
    int e = row_start[n + 1];

    float m = -INFINITY, lsum = 0.f, acc = 0.f;
    for (int i = s; i < e; i++) {
        int sn = src_sorted[i];
        float hs_val = active ? ld_elem(hs, (size_t)sn * HD + fidx) : 0.f;
        float pre = hs_val + hd_val;
        float lr = pre > 0.f ? pre : SLOPE * pre;
        float partial = lr * attn_val;
#pragma unroll
        for (int off = 32; off > 0; off >>= 1)
            partial += __shfl_xor(partial, off, 64);
        float logit = partial;
        if (logit > m) {
            float scale = __expf(m - logit);  // exp(-inf)=0 on first edge
            lsum = lsum * scale + 1.f;
            acc = acc * scale + hs_val;
            m = logit;
        } else {
            float p = __expf(logit - m);
            lsum += p;
            acc += p * hs_val;
        }
    }
    float val = (e > s) ? acc / lsum : 0.f;

    if (FINAL) {
        __shared__ float red[4][64];
        red[h][d] = val;
        __syncthreads();
        if (h == 0 && active) {
            float sum = red[0][d] + red[1][d] + red[2][d] + red[3][d];
            out_final[(size_t)n * D + d] = 0.25f * sum;
        }
    } else {
        if (active) {
            size_t oi = (size_t)n * HD + fidx;
            if (RES_INPLACE) val += ld_elem(out, oi);
            st_elem(out, oi, val);
        }
    }
}

// ---------------- pipeline (templated on activation dtypes) ----------------

struct Ptrs {
    const float *x0, *w_src0, *b_src0, *w_dst0, *b_dst0, *attn0, *w_res0, *b_res0;
    const float *w_src1, *b_src1, *w_dst1, *b_dst1, *attn1;
    const float *w_src2, *b_src2, *w_dst2, *b_dst2, *attn2, *w_res2, *b_res2;
    const int *row_start, *src_sorted;
    float *w_eff, *b_eff, *out;
    int N;
};

template <typename P, typename S>
static void run_pipeline(const Ptrs& p, P* Pbuf, S* HS, S* HD, hipStream_t stream) {
    const int N = p.N;
    dim3 blk(256);
    int mt = (N + 63) / 64;

    // Layer 0: x0 [N,128] -> hs,hd [N,256]; agg -> P; res GEMM-accum into P
    hipLaunchKernelGGL((gemm_bias<float, S, false>), dim3(4, mt), blk, 0, stream,
                       p.x0, p.w_src0, p.b_src0, HS, N, 128, 256);
    hipLaunchKernelGGL((gemm_bias<float, S, false>), dim3(4, mt), blk, 0, stream,
                       p.x0, p.w_dst0, p.b_dst0, HD, N, 128, 256);
    hipLaunchKernelGGL((gat_aggregate<64, false, false, S, P>), dim3(N), blk, 0, stream,
                       HS, HD, p.attn0, p.row_start, p.src_sorted, Pbuf, (float*)nullptr);
    hipLaunchKernelGGL((gemm_bias<float, P, true>), dim3(4, mt), blk, 0, stream,
                       p.x0, p.w_res0, p.b_res0, Pbuf, N, 128, 256);

    // Layer 1: P [N,256] -> hs,hd; agg with identity residual in-place on P
    hipLaunchKernelGGL((gemm_bias<P, S, false>), dim3(4, mt), blk, 0, stream,
                       Pbuf, p.w_src1, p.b_src1, HS, N, 256, 256);
    hipLaunchKernelGGL((gemm_bias<P, S, false>), dim3(4, mt), blk, 0, stream,
                       Pbuf, p.w_dst1, p.b_dst1, HD, N, 256, 256);
    hipLaunchKernelGGL((gat_aggregate<64, false, true, S, P>), dim3(N), blk, 0, stream,
                       HS, HD, p.attn1, p.row_start, p.src_sorted, Pbuf, (float*)nullptr);

    // Layer 2: P [N,256] -> hs,hd [N,160]; agg FINAL -> out (head mean);
    // then folded residual GEMM-accum: out += P @ w_eff + b_eff
    hipLaunchKernelGGL((gemm_bias<P, S, false>), dim3(3, mt), blk, 0, stream,
                       Pbuf, p.w_src2, p.b_src2, HS, N, 256, 160);
    hipLaunchKernelGGL((gemm_bias<P, S, false>), dim3(3, mt), blk, 0, stream,
                       Pbuf, p.w_dst2, p.b_dst2, HD, N, 256, 160);
    hipLaunchKernelGGL((gat_aggregate<40, true, false, S, P>), dim3(N), blk, 0, stream,
                       HS, HD, p.attn2, p.row_start, p.src_sorted, (P*)nullptr, p.out);
    hipLaunchKernelGGL(build_weff, dim3(40), blk, 0, stream,
                       p.w_res2, p.b_res2, p.w_eff, p.b_eff);
    hipLaunchKernelGGL((gemm_bias<P, float, true>), dim3(1, mt), blk, 0, stream,
                       Pbuf, p.w_eff, p.b_eff, p.out, N, 256, 40);
}

// ---------------- launch ----------------

extern "C" void kernel_launch(void* const* d_in, const int* in_sizes, int n_in,
                              void* d_out, int out_size, void* d_ws, size_t ws_size,
                              hipStream_t stream) {
    Ptrs p;
    p.x0     = (const float*)d_in[0];
    const int* src = (const int*)d_in[1];
    const int* dst = (const int*)d_in[2];
    p.w_src0 = (const float*)d_in[3];  p.b_src0 = (const float*)d_in[4];
    p.w_dst0 = (const float*)d_in[5];  p.b_dst0 = (const float*)d_in[6];
    p.attn0  = (const float*)d_in[7];
    p.w_res0 = (const float*)d_in[8];  p.b_res0 = (const float*)d_in[9];
    p.w_src1 = (const float*)d_in[10]; p.b_src1 = (const float*)d_in[11];
    p.w_dst1 = (const float*)d_in[12]; p.b_dst1 = (const float*)d_in[13];
    p.attn1  = (const float*)d_in[14];
    p.w_src2 = (const float*)d_in[15]; p.b_src2 = (const float*)d_in[16];
    p.w_dst2 = (const float*)d_in[17]; p.b_dst2 = (const float*)d_in[18];
    p.attn2  = (const float*)d_in[19];
    p.w_res2 = (const float*)d_in[20]; p.b_res2 = (const float*)d_in[21];

    const int N = in_sizes[0] / 128;   // 50000
    const int E = in_sizes[1];         // 400000
    p.N = N;
    p.out = (float*)d_out;
    (void)n_in; (void)out_size;

    // ---- fixed workspace (CSR + folded weights) ----
    char* ws = (char*)d_ws;
    size_t off = 0;
    auto alloc = [&](size_t bytes) {
        void* q = ws + off;
        off = (off + bytes + 255) & ~(size_t)255;
        return q;
    };
    int* deg        = (int*)alloc((size_t)2 * N * 4);  // deg + fill contiguous
    int* fill       = deg + N;
    int* row_start  = (int*)alloc((size_t)(N + 1) * 4);
    int* chunk_sums = (int*)alloc(256 * 4);
    int* src_sorted = (int*)alloc((size_t)E * 4);
    p.w_eff = (float*)alloc(256 * 40 * 4);
    p.b_eff = (float*)alloc(64 * 4);
    p.row_start = row_start;
    p.src_sorted = src_sorted;

    size_t fixed = off;
    const size_t elems = (size_t)N * 256;
    // tier footprints: P + HS + HD (+256B alignment slack each)
    size_t tier0 = fixed + 3 * (elems * 4 + 256);            // all f32
    size_t tier1 = fixed + elems * 4 + 2 * elems * 2 + 768;  // P f32, staging bf16
    // tier2 (all bf16) is the fallback

    // ---- CSR build (graph identical across layers) ----
    hipMemsetAsync(deg, 0, (size_t)2 * N * 4, stream);
    int eblocks = (E + 255) / 256;
    int nchunks = (N + 1023) / 1024;
    hipLaunchKernelGGL(hist_dst, dim3(eblocks), dim3(256), 0, stream, dst, E, deg);
    hipLaunchKernelGGL(deg_chunk_sum, dim3(nchunks), dim3(256), 0, stream, deg, N, chunk_sums);
    hipLaunchKernelGGL(scan_chunk_sums, dim3(1), dim3(256), 0, stream, chunk_sums, nchunks);
    hipLaunchKernelGGL(scan_write, dim3(nchunks), dim3(256), 0, stream, deg, N, chunk_sums, row_start, E);
    hipLaunchKernelGGL(scatter_edges, dim3(eblocks), dim3(256), 0, stream, dst, src, E, row_start, fill, src_sorted);

    // ---- pick precision tier that fits ws_size ----
    if (ws_size >= tier0) {
        float* Pb = (float*)alloc(elems * 4);
        float* HS = (float*)alloc(elems * 4);
        float* HD = (float*)alloc(elems * 4);
        run_pipeline<float, float>(p, Pb, HS, HD, stream);
    } else if (ws_size >= tier1) {
        float*  Pb = (float*)alloc(elems * 4);
        bf16_t* HS = (bf16_t*)alloc(elems * 2);
        bf16_t* HD = (bf16_t*)alloc(elems * 2);
        run_pipeline<float, bf16_t>(p, Pb, HS, HD, stream);
    } else {
        bf16_t* Pb = (bf16_t*)alloc(elems * 2);
        bf16_t* HS = (bf16_t*)alloc(elems * 2);
        bf16_t* HD = (bf16_t*)alloc(elems * 2);
        run_pipeline<bf16_t, bf16_t>(p, Pb, HS, HD, stream);
    }
}

// Round 3
// 677.729 us; speedup vs baseline: 1.9312x; 1.9312x over previous
//
#include <hip/hip_runtime.h>
#include <math.h>

// N=50000, E=400000, F_IN=128, HID=64, OUT=40, H=4
#define SLOPE 0.2f

typedef unsigned short bf16_t;
typedef short bh8 __attribute__((ext_vector_type(8)));
typedef float f32x4 __attribute__((ext_vector_type(4)));

__device__ __forceinline__ float bf2f(bf16_t x) {
    return __uint_as_float((unsigned)x << 16);
}
__device__ __forceinline__ bf16_t f2bf(float v) {
    unsigned u = __float_as_uint(v);
    return (bf16_t)((u + 0x7FFFu + ((u >> 16) & 1u)) >> 16);  // RNE
}
__device__ __forceinline__ float ld_elem(const float* p, size_t i) { return p[i]; }
__device__ __forceinline__ float ld_elem(const bf16_t* p, size_t i) { return bf2f(p[i]); }
__device__ __forceinline__ void st_elem(float* p, size_t i, float v) { p[i] = v; }
__device__ __forceinline__ void st_elem(bf16_t* p, size_t i, float v) { p[i] = f2bf(v); }

// ---------------- CSR build (unchanged from R2 — verified) ----------------

__global__ void hist_dst(const int* __restrict__ dst, int E, int* __restrict__ deg) {
    int e = blockIdx.x * 256 + threadIdx.x;
    if (e < E) atomicAdd(&deg[dst[e]], 1);
}

__global__ void deg_chunk_sum(const int* __restrict__ deg, int n, int* __restrict__ chunk_sums) {
    __shared__ int sm[256];
    int base = blockIdx.x * 1024;
    int s = 0;
    for (int i = threadIdx.x; i < 1024; i += 256) {
        int idx = base + i;
        if (idx < n) s += deg[idx];
    }
    sm[threadIdx.x] = s;
    __syncthreads();
    for (int off = 128; off > 0; off >>= 1) {
        if (threadIdx.x < off) sm[threadIdx.x] += sm[threadIdx.x + off];
        __syncthreads();
    }
    if (threadIdx.x == 0) chunk_sums[blockIdx.x] = sm[0];
}

__global__ void scan_chunk_sums(int* __restrict__ chunk_sums, int nchunks) {
    __shared__ int sm[256];
    int t = threadIdx.x;
    if (t < nchunks) sm[t] = chunk_sums[t];
    __syncthreads();
    if (t == 0) {
        int run = 0;
        for (int i = 0; i < nchunks; i++) { int v = sm[i]; sm[i] = run; run += v; }
    }
    __syncthreads();
    if (t < nchunks) chunk_sums[t] = sm[t];
}

__global__ void scan_write(const int* __restrict__ deg, int n,
                           const int* __restrict__ chunk_sums,
                           int* __restrict__ row_start, int Etot) {
    int base = blockIdx.x * 1024;
    int t = threadIdx.x;
    int v[4];
    int tsum = 0;
#pragma unroll
    for (int j = 0; j < 4; j++) {
        int idx = base + t * 4 + j;
        v[j] = (idx < n) ? deg[idx] : 0;
        tsum += v[j];
    }
    __shared__ int sm[256];
    sm[t] = tsum;
    __syncthreads();
    for (int off = 1; off < 256; off <<= 1) {
        int x = (t >= off) ? sm[t - off] : 0;
        __syncthreads();
        sm[t] += x;
        __syncthreads();
    }
    int excl = sm[t] - tsum + chunk_sums[blockIdx.x];
#pragma unroll
    for (int j = 0; j < 4; j++) {
        int idx = base + t * 4 + j;
        if (idx < n) row_start[idx] = excl;
        excl += v[j];
    }
    if (blockIdx.x == 0 && t == 0) row_start[n] = Etot;
}

__global__ void scatter_edges(const int* __restrict__ dst, const int* __restrict__ src, int E,
                              const int* __restrict__ row_start,
                              int* __restrict__ fill, int* __restrict__ src_sorted) {
    int e = blockIdx.x * 256 + threadIdx.x;
    if (e < E) {
        int d_ = dst[e];
        int pos = row_start[d_] + atomicAdd(&fill[d_], 1);
        src_sorted[pos] = src[e];
    }
}

// ---------------- weight conversion: W[K][Nc] f32 -> Wt[Npad][K] bf16 ----------------
// One kernel, block-range dispatch over all 7 weights + w_eff head-fold.
// Segments: [0,384) L0 (3 x 128 blk, Npad=256,K=128); [384,896) L1 (2 x 256 blk, 256x256);
// [896,1280) L2 (2 x 192 blk, Npad=192,K=256,Nc=160); [1280,1344) w_eff (64 blk, 64x256).

__global__ void convert_weights(
    const float* __restrict__ w0, const float* __restrict__ w1, const float* __restrict__ w2,
    const float* __restrict__ w3, const float* __restrict__ w4,
    const float* __restrict__ w5, const float* __restrict__ w6,
    const float* __restrict__ wr2, const float* __restrict__ br2,
    bf16_t* __restrict__ t0, bf16_t* __restrict__ t1, bf16_t* __restrict__ t2,
    bf16_t* __restrict__ t3, bf16_t* __restrict__ t4,
    bf16_t* __restrict__ t5, bf16_t* __restrict__ t6,
    bf16_t* __restrict__ teff, float* __restrict__ b_eff)
{
    int b = blockIdx.x, t = threadIdx.x;
    const float* W; bf16_t* T; int K, Nc, lb;
    if (b < 384) {
        int g = b / 128; lb = b - g * 128;
        W = g == 0 ? w0 : (g == 1 ? w1 : w2);
        T = g == 0 ? t0 : (g == 1 ? t1 : t2);
        K = 128; Nc = 256;
    } else if (b < 896) {
        int g = (b - 384) / 256; lb = (b - 384) - g * 256;
        W = g == 0 ? w3 : w4; T = g == 0 ? t3 : t4;
        K = 256; Nc = 256;
    } else if (b < 1280) {
        int g = (b - 896) / 192; lb = (b - 896) - g * 192;
        W = g == 0 ? w5 : w6; T = g == 0 ? t5 : t6;
        K = 256; Nc = 160;
    } else {
        lb = b - 1280;
        int idx = lb * 256 + t;          // 64*256 = 16384 elems
        int n = idx >> 8, k = idx & 255;
        float v = 0.f;
        if (n < 40)
            v = 0.25f * (wr2[(size_t)k * 160 + n] + wr2[(size_t)k * 160 + 40 + n] +
                         wr2[(size_t)k * 160 + 80 + n] + wr2[(size_t)k * 160 + 120 + n]);
        teff[idx] = f2bf(v);
        if (lb == 0 && t < 40)
            b_eff[t] = 0.25f * (br2[t] + br2[40 + t] + br2[80 + t] + br2[120 + t]);
        return;
    }
    int idx = lb * 256 + t;
    int n = idx / K, k = idx - n * K;   // Wt row n (output col), col k
    float v = (n < Nc) ? W[(size_t)k * Nc + n] : 0.f;
    T[idx] = f2bf(v);
}

// ---------------- bf16 MFMA GEMM: C[M,Nc] (+)= A[M,K] @ W + bias ----------------
// Wt is pre-transposed bf16 [Npad][K] (Npad = gridDim.x*64, zero-padded rows).
// Block tile 128x64, BK=64, 4 waves as 2x2 (wave tile 64x32).
// mfma_f32_16x16x32_bf16: A frag m=lane&15,k=quad*8+j; B frag from Wt row n=lane&15;
// C/D col=lane&15, row=quad*4+reg  [verified m89/m91].
// SPLIT40: store col remap f = gn + 24*(gn/40), row stride 256 (head-pad to 64).

template <typename TA, typename TC, bool ACCUM, bool SPLIT40>
__global__ __launch_bounds__(256) void gemm_mfma(
    const TA* __restrict__ A, const bf16_t* __restrict__ Wt,
    const float* __restrict__ bias, TC* __restrict__ C,
    int M, int K, int Nc)
{
    __shared__ bf16_t As[128 * 72];   // 128 rows x 64 k, stride 72 (+8 pad)
    int tid = threadIdx.x;
    int lane = tid & 63, w = tid >> 6;
    int wm = w >> 1, wn = w & 1;
    int lq = lane >> 4, lm = lane & 15;
    int m0 = blockIdx.y * 128, n0 = blockIdx.x * 64;

    f32x4 acc[4][2];
#pragma unroll
    for (int i = 0; i < 4; i++)
#pragma unroll
        for (int j = 0; j < 2; j++)
            acc[i][j] = (f32x4){0.f, 0.f, 0.f, 0.f};

    for (int k0 = 0; k0 < K; k0 += 64) {
        // ---- stage A tile (convert f32->bf16 on the fly if needed) ----
        if (sizeof(TA) == 4) {
#pragma unroll
            for (int i = 0; i < 8; i++) {
                int idx = tid + i * 256;          // 2048 float4 chunks
                int r = idx >> 4, c4 = idx & 15;
                int gm = m0 + r;
                float4 v = {0.f, 0.f, 0.f, 0.f};
                if (gm < M) v = *(const float4*)((const float*)A + (size_t)gm * K + k0 + c4 * 4);
                ushort4 pk = { f2bf(v.x), f2bf(v.y), f2bf(v.z), f2bf(v.w) };
                *(ushort4*)(As + r * 72 + c4 * 4) = pk;
            }
        } else {
#pragma unroll
            for (int i = 0; i < 4; i++) {
                int idx = tid + i * 256;          // 1024 8-elem chunks
                int r = idx >> 3, c8 = idx & 7;
                int gm = m0 + r;
                bh8 v = {};
                if (gm < M) v = *(const bh8*)((const bf16_t*)A + (size_t)gm * K + k0 + c8 * 8);
                *(bh8*)(As + r * 72 + c8 * 8) = v;
            }
        }
        __syncthreads();
#pragma unroll
        for (int kc = 0; kc < 2; kc++) {
            bh8 af[4], bf[2];
#pragma unroll
            for (int mt = 0; mt < 4; mt++)
                af[mt] = *(const bh8*)(As + (wm * 64 + mt * 16 + lm) * 72 + kc * 32 + lq * 8);
#pragma unroll
            for (int nt = 0; nt < 2; nt++)
                bf[nt] = *(const bh8*)(Wt + (size_t)(n0 + wn * 32 + nt * 16 + lm) * K + k0 + kc * 32 + lq * 8);
#pragma unroll
            for (int mt = 0; mt < 4; mt++)
#pragma unroll
                for (int nt = 0; nt < 2; nt++)
                    acc[mt][nt] = __builtin_amdgcn_mfma_f32_16x16x32_bf16(af[mt], bf[nt], acc[mt][nt], 0, 0, 0);
        }
        __syncthreads();
    }
    // ---- epilogue ----
#pragma unroll
    for (int nt = 0; nt < 2; nt++) {
        int gn = n0 + wn * 32 + nt * 16 + lm;
        if (gn >= Nc) continue;
        float bv = bias[gn];
        size_t cb = SPLIT40 ? (size_t)(gn + 24 * (gn / 40)) : (size_t)gn;
#pragma unroll
        for (int mt = 0; mt < 4; mt++) {
#pragma unroll
            for (int r = 0; r < 4; r++) {
                int gm = m0 + wm * 64 + mt * 16 + lq * 4 + r;
                if (gm >= M) continue;
                size_t ci = SPLIT40 ? ((size_t)gm * 256 + cb) : ((size_t)gm * Nc + cb);
                float v = acc[mt][nt][r] + bv;
                if (ACCUM) v += ld_elem(C, ci);
                st_elem(C, ci, v);
            }
        }
    }
}

// ---------------- GATv2 aggregation: one block/node, 4 waves split edges ----------------
// All buffers stride 256 (head stride 64, padded for DVALID=40; attn=0 on pad cols).
// Each wave: every 4th edge, full row (4 bf16/lane), segmented 16-lane reduce per head,
// per-wave online softmax; LDS merge of (m,l,acc) across waves.

template <int DVALID, bool FINAL, bool RES_INPLACE>
__global__ __launch_bounds__(256) void gat_agg(
    const bf16_t* __restrict__ hs, const bf16_t* __restrict__ hd,
    const float* __restrict__ attn,
    const int* __restrict__ row_start, const int* __restrict__ src_sorted,
    bf16_t* __restrict__ P, float* __restrict__ out_final)
{
    __shared__ float s_acc[4][256];
    __shared__ float s_m[4][4], s_l[4][4];
    int n = blockIdx.x, t = threadIdx.x;
    int w = t >> 6, l = t & 63;
    int h = l >> 4;            // head owning this lane's 4 features
    int f0 = 4 * l;            // padded feature base
    int dp = 4 * (l & 15);     // d within head (padded space)

    float at[4], hdf[4];
    ushort4 hv = *(const ushort4*)(hd + (size_t)n * 256 + f0);
    hdf[0] = bf2f(hv.x); hdf[1] = bf2f(hv.y); hdf[2] = bf2f(hv.z); hdf[3] = bf2f(hv.w);
#pragma unroll
    for (int j = 0; j < 4; j++)
        at[j] = (dp + j < DVALID) ? attn[h * DVALID + dp + j] : 0.f;

    int s = row_start[n], e = row_start[n + 1];
    float m = -INFINITY, lsum = 0.f;
    float acc[4] = {0.f, 0.f, 0.f, 0.f};
    for (int i = s + w; i < e; i += 4) {
        int sn = src_sorted[i];
        ushort4 sv = *(const ushort4*)(hs + (size_t)sn * 256 + f0);
        float hsf[4] = { bf2f(sv.x), bf2f(sv.y), bf2f(sv.z), bf2f(sv.w) };
        float partial = 0.f;
#pragma unroll
        for (int j = 0; j < 4; j++) {
            float pre = hsf[j] + hdf[j];
            float lr = pre > 0.f ? pre : SLOPE * pre;
            partial += lr * at[j];
        }
        partial += __shfl_xor(partial, 1, 64);
        partial += __shfl_xor(partial, 2, 64);
        partial += __shfl_xor(partial, 4, 64);
        partial += __shfl_xor(partial, 8, 64);
        float logit = partial;  // replicated across the 16-lane head group
        if (logit > m) {
            float sc = __expf(m - logit);   // exp(-inf)=0 on first edge
            lsum = lsum * sc + 1.f;
#pragma unroll
            for (int j = 0; j < 4; j++) acc[j] = acc[j] * sc + hsf[j];
            m = logit;
        } else {
            float p = __expf(logit - m);
            lsum += p;
#pragma unroll
            for (int j = 0; j < 4; j++) acc[j] += p * hsf[j];
        }
    }
    *(float4*)&s_acc[w][f0] = (float4){acc[0], acc[1], acc[2], acc[3]};
    if ((l & 15) == 0) { s_m[w][h] = m; s_l[w][h] = lsum; }
    __syncthreads();

    // merge: thread t owns padded feature f=t, head hh=t>>6 (uniform per wave)
    int hh = t >> 6;
    float val = 0.f;
    if (e > s) {
        float M = fmaxf(fmaxf(s_m[0][hh], s_m[1][hh]), fmaxf(s_m[2][hh], s_m[3][hh]));
        float L = 0.f, Av = 0.f;
#pragma unroll
        for (int ww = 0; ww < 4; ww++) {
            float sc = __expf(s_m[ww][hh] - M);  // m=-inf (idle wave) -> 0
            L  += sc * s_l[ww][hh];
            Av += sc * s_acc[ww][t];
        }
        val = Av / L;
    }
    if (FINAL) {
        __syncthreads();
        s_acc[0][t] = val;
        __syncthreads();
        if (t < DVALID)
            out_final[(size_t)n * DVALID + t] =
                0.25f * (s_acc[0][t] + s_acc[0][64 + t] + s_acc[0][128 + t] + s_acc[0][192 + t]);
    } else {
        size_t oi = (size_t)n * 256 + t;
        float v = val;
        if (RES_INPLACE) v += bf2f(P[oi]);
        P[oi] = f2bf(v);
    }
}

// ---------------- launch ----------------

extern "C" void kernel_launch(void* const* d_in, const int* in_sizes, int n_in,
                              void* d_out, int out_size, void* d_ws, size_t ws_size,
                              hipStream_t stream) {
    const float* x0    = (const float*)d_in[0];
    const int*   src   = (const int*)d_in[1];
    const int*   dst   = (const int*)d_in[2];
    const float* w_src0 = (const float*)d_in[3];  const float* b_src0 = (const float*)d_in[4];
    const float* w_dst0 = (const float*)d_in[5];  const float* b_dst0 = (const float*)d_in[6];
    const float* attn0  = (const float*)d_in[7];
    const float* w_res0 = (const float*)d_in[8];  const float* b_res0 = (const float*)d_in[9];
    const float* w_src1 = (const float*)d_in[10]; const float* b_src1 = (const float*)d_in[11];
    const float* w_dst1 = (const float*)d_in[12]; const float* b_dst1 = (const float*)d_in[13];
    const float* attn1  = (const float*)d_in[14];
    const float* w_src2 = (const float*)d_in[15]; const float* b_src2 = (const float*)d_in[16];
    const float* w_dst2 = (const float*)d_in[17]; const float* b_dst2 = (const float*)d_in[18];
    const float* attn2  = (const float*)d_in[19];
    const float* w_res2 = (const float*)d_in[20]; const float* b_res2 = (const float*)d_in[21];

    const int N = in_sizes[0] / 128;   // 50000
    const int E = in_sizes[1];         // 400000
    float* out = (float*)d_out;
    (void)n_in; (void)out_size; (void)ws_size;

    // ---- workspace (~79.7 MB total) ----
    char* ws = (char*)d_ws;
    size_t off = 0;
    auto alloc = [&](size_t bytes) {
        void* q = ws + off;
        off = (off + bytes + 255) & ~(size_t)255;
        return q;
    };
    int* deg        = (int*)alloc((size_t)2 * N * 4);  // deg + fill contiguous
    int* fill       = deg + N;
    int* row_start  = (int*)alloc((size_t)(N + 1) * 4);
    int* chunk_sums = (int*)alloc(256 * 4);
    int* src_sorted = (int*)alloc((size_t)E * 4);
    bf16_t* t_src0 = (bf16_t*)alloc(256 * 128 * 2);
    bf16_t* t_dst0 = (bf16_t*)alloc(256 * 128 * 2);
    bf16_t* t_res0 = (bf16_t*)alloc(256 * 128 * 2);
    bf16_t* t_src1 = (bf16_t*)alloc(256 * 256 * 2);
    bf16_t* t_dst1 = (bf16_t*)alloc(256 * 256 * 2);
    bf16_t* t_src2 = (bf16_t*)alloc(192 * 256 * 2);
    bf16_t* t_dst2 = (bf16_t*)alloc(192 * 256 * 2);
    bf16_t* t_eff  = (bf16_t*)alloc(64 * 256 * 2);
    float*  b_eff  = (float*)alloc(64 * 4);
    const size_t elems = (size_t)N * 256;
    bf16_t* P  = (bf16_t*)alloc(elems * 2);
    bf16_t* HS = (bf16_t*)alloc(elems * 2);
    bf16_t* HD = (bf16_t*)alloc(elems * 2);

    // ---- CSR build + weight conversion ----
    hipMemsetAsync(deg, 0, (size_t)2 * N * 4, stream);
    int eblocks = (E + 255) / 256;
    int nchunks = (N + 1023) / 1024;
    hipLaunchKernelGGL(hist_dst, dim3(eblocks), dim3(256), 0, stream, dst, E, deg);
    hipLaunchKernelGGL(convert_weights, dim3(1344), dim3(256), 0, stream,
                       w_src0, w_dst0, w_res0, w_src1, w_dst1, w_src2, w_dst2, w_res2, b_res2,
                       t_src0, t_dst0, t_res0, t_src1, t_dst1, t_src2, t_dst2, t_eff, b_eff);
    hipLaunchKernelGGL(deg_chunk_sum, dim3(nchunks), dim3(256), 0, stream, deg, N, chunk_sums);
    hipLaunchKernelGGL(scan_chunk_sums, dim3(1), dim3(256), 0, stream, chunk_sums, nchunks);
    hipLaunchKernelGGL(scan_write, dim3(nchunks), dim3(256), 0, stream, deg, N, chunk_sums, row_start, E);
    hipLaunchKernelGGL(scatter_edges, dim3(eblocks), dim3(256), 0, stream, dst, src, E, row_start, fill, src_sorted);

    dim3 blk(256);
    int mb = (N + 127) / 128;   // 391

    // ---- Layer 0: x0[N,128] (f32 A) ----
    hipLaunchKernelGGL((gemm_mfma<float, bf16_t, false, false>), dim3(4, mb), blk, 0, stream,
                       x0, t_src0, b_src0, HS, N, 128, 256);
    hipLaunchKernelGGL((gemm_mfma<float, bf16_t, false, false>), dim3(4, mb), blk, 0, stream,
                       x0, t_dst0, b_dst0, HD, N, 128, 256);
    hipLaunchKernelGGL((gat_agg<64, false, false>), dim3(N), blk, 0, stream,
                       HS, HD, attn0, row_start, src_sorted, P, (float*)nullptr);
    hipLaunchKernelGGL((gemm_mfma<float, bf16_t, true, false>), dim3(4, mb), blk, 0, stream,
                       x0, t_res0, b_res0, P, N, 128, 256);

    // ---- Layer 1: P[N,256] bf16, identity residual in-place ----
    hipLaunchKernelGGL((gemm_mfma<bf16_t, bf16_t, false, false>), dim3(4, mb), blk, 0, stream,
                       P, t_src1, b_src1, HS, N, 256, 256);
    hipLaunchKernelGGL((gemm_mfma<bf16_t, bf16_t, false, false>), dim3(4, mb), blk, 0, stream,
                       P, t_dst1, b_dst1, HD, N, 256, 256);
    hipLaunchKernelGGL((gat_agg<64, false, true>), dim3(N), blk, 0, stream,
                       HS, HD, attn1, row_start, src_sorted, P, (float*)nullptr);

    // ---- Layer 2: SPLIT40 staging (head-padded cols), FINAL agg -> out, res-fold accum ----
    hipLaunchKernelGGL((gemm_mfma<bf16_t, bf16_t, false, true>), dim3(3, mb), blk, 0, stream,
                       P, t_src2, b_src2, HS, N, 256, 160);
    hipLaunchKernelGGL((gemm_mfma<bf16_t, bf16_t, false, true>), dim3(3, mb), blk, 0, stream,
                       P, t_dst2, b_dst2, HD, N, 256, 160);
    hipLaunchKernelGGL((gat_agg<40, true, false>), dim3(N), blk, 0, stream,
                       HS, HD, attn2, row_start, src_sorted, (bf16_t*)nullptr, out);
    hipLaunchKernelGGL((gemm_mfma<bf16_t, float, true, false>), dim3(1, mb), blk, 0, stream,
                       P, t_eff, b_eff, out, N, 256, 40);
}

// Round 4
// 542.488 us; speedup vs baseline: 2.4126x; 1.2493x over previous
//
#include <hip/hip_runtime.h>
#include <math.h>

// N=50000, E=400000, F_IN=128, HID=64, OUT=40, H=4
#define SLOPE 0.2f

typedef unsigned short bf16_t;
typedef short bh8 __attribute__((ext_vector_type(8)));
typedef float f32x4 __attribute__((ext_vector_type(4)));

__device__ __forceinline__ float bf2f(bf16_t x) {
    return __uint_as_float((unsigned)x << 16);
}
__device__ __forceinline__ bf16_t f2bf(float v) {
    unsigned u = __float_as_uint(v);
    return (bf16_t)((u + 0x7FFFu + ((u >> 16) & 1u)) >> 16);  // RNE
}
__device__ __forceinline__ float ld_elem(const float* p, size_t i) { return p[i]; }
__device__ __forceinline__ float ld_elem(const bf16_t* p, size_t i) { return bf2f(p[i]); }
__device__ __forceinline__ void st_elem(float* p, size_t i, float v) { p[i] = v; }
__device__ __forceinline__ void st_elem(bf16_t* p, size_t i, float v) { p[i] = f2bf(v); }

// ---------------- CSR build (verified R2/R3) ----------------

__global__ void hist_dst(const int* __restrict__ dst, int E, int* __restrict__ deg) {
    int e = blockIdx.x * 256 + threadIdx.x;
    if (e < E) atomicAdd(&deg[dst[e]], 1);
}

__global__ void deg_chunk_sum(const int* __restrict__ deg, int n, int* __restrict__ chunk_sums) {
    __shared__ int sm[256];
    int base = blockIdx.x * 1024;
    int s = 0;
    for (int i = threadIdx.x; i < 1024; i += 256) {
        int idx = base + i;
        if (idx < n) s += deg[idx];
    }
    sm[threadIdx.x] = s;
    __syncthreads();
    for (int off = 128; off > 0; off >>= 1) {
        if (threadIdx.x < off) sm[threadIdx.x] += sm[threadIdx.x + off];
        __syncthreads();
    }
    if (threadIdx.x == 0) chunk_sums[blockIdx.x] = sm[0];
}

__global__ void scan_chunk_sums(int* __restrict__ chunk_sums, int nchunks) {
    __shared__ int sm[256];
    int t = threadIdx.x;
    if (t < nchunks) sm[t] = chunk_sums[t];
    __syncthreads();
    if (t == 0) {
        int run = 0;
        for (int i = 0; i < nchunks; i++) { int v = sm[i]; sm[i] = run; run += v; }
    }
    __syncthreads();
    if (t < nchunks) chunk_sums[t] = sm[t];
}

__global__ void scan_write(const int* __restrict__ deg, int n,
                           const int* __restrict__ chunk_sums,
                           int* __restrict__ row_start, int Etot) {
    int base = blockIdx.x * 1024;
    int t = threadIdx.x;
    int v[4];
    int tsum = 0;
#pragma unroll
    for (int j = 0; j < 4; j++) {
        int idx = base + t * 4 + j;
        v[j] = (idx < n) ? deg[idx] : 0;
        tsum += v[j];
    }
    __shared__ int sm[256];
    sm[t] = tsum;
    __syncthreads();
    for (int off = 1; off < 256; off <<= 1) {
        int x = (t >= off) ? sm[t - off] : 0;
        __syncthreads();
        sm[t] += x;
        __syncthreads();
    }
    int excl = sm[t] - tsum + chunk_sums[blockIdx.x];
#pragma unroll
    for (int j = 0; j < 4; j++) {
        int idx = base + t * 4 + j;
        if (idx < n) row_start[idx] = excl;
        excl += v[j];
    }
    if (blockIdx.x == 0 && t == 0) row_start[n] = Etot;
}

__global__ void scatter_edges(const int* __restrict__ dst, const int* __restrict__ src, int E,
                              const int* __restrict__ row_start,
                              int* __restrict__ fill, int* __restrict__ src_sorted) {
    int e = blockIdx.x * 256 + threadIdx.x;
    if (e < E) {
        int d_ = dst[e];
        int pos = row_start[d_] + atomicAdd(&fill[d_], 1);
        src_sorted[pos] = src[e];
    }
}

// ---------------- weight conversion: W[K][Nc] f32 -> Wt[Npad][K] bf16 (verified R3) ----------------

__global__ void convert_weights(
    const float* __restrict__ w0, const float* __restrict__ w1, const float* __restrict__ w2,
    const float* __restrict__ w3, const float* __restrict__ w4,
    const float* __restrict__ w5, const float* __restrict__ w6,
    const float* __restrict__ wr2, const float* __restrict__ br2,
    bf16_t* __restrict__ t0, bf16_t* __restrict__ t1, bf16_t* __restrict__ t2,
    bf16_t* __restrict__ t3, bf16_t* __restrict__ t4,
    bf16_t* __restrict__ t5, bf16_t* __restrict__ t6,
    bf16_t* __restrict__ teff, float* __restrict__ b_eff)
{
    int b = blockIdx.x, t = threadIdx.x;
    const float* W; bf16_t* T; int K, Nc, lb;
    if (b < 384) {
        int g = b / 128; lb = b - g * 128;
        W = g == 0 ? w0 : (g == 1 ? w1 : w2);
        T = g == 0 ? t0 : (g == 1 ? t1 : t2);
        K = 128; Nc = 256;
    } else if (b < 896) {
        int g = (b - 384) / 256; lb = (b - 384) - g * 256;
        W = g == 0 ? w3 : w4; T = g == 0 ? t3 : t4;
        K = 256; Nc = 256;
    } else if (b < 1280) {
        int g = (b - 896) / 192; lb = (b - 896) - g * 192;
        W = g == 0 ? w5 : w6; T = g == 0 ? t5 : t6;
        K = 256; Nc = 160;
    } else {
        lb = b - 1280;
        int idx = lb * 256 + t;          // 64*256 = 16384 elems
        int n = idx >> 8, k = idx & 255;
        float v = 0.f;
        if (n < 40)
            v = 0.25f * (wr2[(size_t)k * 160 + n] + wr2[(size_t)k * 160 + 40 + n] +
                         wr2[(size_t)k * 160 + 80 + n] + wr2[(size_t)k * 160 + 120 + n]);
        teff[idx] = f2bf(v);
        if (lb == 0 && t < 40)
            b_eff[t] = 0.25f * (br2[t] + br2[40 + t] + br2[80 + t] + br2[120 + t]);
        return;
    }
    int idx = lb * 256 + t;
    int n = idx / K, k = idx - n * K;
    float v = (n < Nc) ? W[(size_t)k * Nc + n] : 0.f;
    T[idx] = f2bf(v);
}

// ---------------- fused multi-output bf16 MFMA GEMM ----------------
// A tile staged ONCE per block; NOUT weight tensors consumed against it.
// Block tile 128x64, BK=64, 4 waves 2x2 (wave tile 64x32).
// SPLIT40: col remap f = gn + 24*(gn/40), row stride 256 (head-pad to 64).

template <typename TA, int NOUT, bool SPLIT40>
__global__ __launch_bounds__(256) void gemm_fused(
    const TA* __restrict__ A,
    const bf16_t* __restrict__ Wt0, const bf16_t* __restrict__ Wt1, const bf16_t* __restrict__ Wt2,
    const float* __restrict__ bias0, const float* __restrict__ bias1, const float* __restrict__ bias2,
    bf16_t* __restrict__ C0, bf16_t* __restrict__ C1, bf16_t* __restrict__ C2,
    int M, int K, int Nc)
{
    __shared__ bf16_t As[128 * 72];   // 128 rows x 64 k, stride 72
    const bf16_t* Wts[3] = {Wt0, Wt1, Wt2};
    const float* biases[3] = {bias0, bias1, bias2};
    bf16_t* Cs[3] = {C0, C1, C2};

    int tid = threadIdx.x;
    int lane = tid & 63, w = tid >> 6;
    int wm = w >> 1, wn = w & 1;
    int lq = lane >> 4, lm = lane & 15;
    int m0 = blockIdx.y * 128, n0 = blockIdx.x * 64;

    f32x4 acc[NOUT][4][2];
#pragma unroll
    for (int o = 0; o < NOUT; o++)
#pragma unroll
        for (int i = 0; i < 4; i++)
#pragma unroll
            for (int j = 0; j < 2; j++)
                acc[o][i][j] = (f32x4){0.f, 0.f, 0.f, 0.f};

    for (int k0 = 0; k0 < K; k0 += 64) {
        if (sizeof(TA) == 4) {
#pragma unroll
            for (int i = 0; i < 8; i++) {
                int idx = tid + i * 256;
                int r = idx >> 4, c4 = idx & 15;
                int gm = m0 + r;
                float4 v = {0.f, 0.f, 0.f, 0.f};
                if (gm < M) v = *(const float4*)((const float*)A + (size_t)gm * K + k0 + c4 * 4);
                ushort4 pk = { f2bf(v.x), f2bf(v.y), f2bf(v.z), f2bf(v.w) };
                *(ushort4*)(As + r * 72 + c4 * 4) = pk;
            }
        } else {
#pragma unroll
            for (int i = 0; i < 4; i++) {
                int idx = tid + i * 256;
                int r = idx >> 3, c8 = idx & 7;
                int gm = m0 + r;
                bh8 v = {};
                if (gm < M) v = *(const bh8*)((const bf16_t*)A + (size_t)gm * K + k0 + c8 * 8);
                *(bh8*)(As + r * 72 + c8 * 8) = v;
            }
        }
        __syncthreads();
#pragma unroll
        for (int kc = 0; kc < 2; kc++) {
            bh8 af[4];
#pragma unroll
            for (int mt = 0; mt < 4; mt++)
                af[mt] = *(const bh8*)(As + (wm * 64 + mt * 16 + lm) * 72 + kc * 32 + lq * 8);
#pragma unroll
            for (int o = 0; o < NOUT; o++) {
                bh8 bf[2];
#pragma unroll
                for (int nt = 0; nt < 2; nt++)
                    bf[nt] = *(const bh8*)(Wts[o] + (size_t)(n0 + wn * 32 + nt * 16 + lm) * K + k0 + kc * 32 + lq * 8);
#pragma unroll
                for (int mt = 0; mt < 4; mt++)
#pragma unroll
                    for (int nt = 0; nt < 2; nt++)
                        acc[o][mt][nt] = __builtin_amdgcn_mfma_f32_16x16x32_bf16(af[mt], bf[nt], acc[o][mt][nt], 0, 0, 0);
            }
        }
        __syncthreads();
    }
#pragma unroll
    for (int o = 0; o < NOUT; o++) {
#pragma unroll
        for (int nt = 0; nt < 2; nt++) {
            int gn = n0 + wn * 32 + nt * 16 + lm;
            if (gn >= Nc) continue;
            float bv = biases[o][gn];
            size_t cb = SPLIT40 ? (size_t)(gn + 24 * (gn / 40)) : (size_t)gn;
#pragma unroll
            for (int mt = 0; mt < 4; mt++) {
#pragma unroll
                for (int r = 0; r < 4; r++) {
                    int gm = m0 + wm * 64 + mt * 16 + lq * 4 + r;
                    if (gm >= M) continue;
                    size_t ci = SPLIT40 ? ((size_t)gm * 256 + cb) : ((size_t)gm * Nc + cb);
                    st_elem(Cs[o], ci, acc[o][mt][nt][r] + bv);
                }
            }
        }
    }
}

// ---- single-output GEMM for the folded residual (writes f32, with bias) ----
__global__ __launch_bounds__(256) void gemm_eff(
    const bf16_t* __restrict__ A, const bf16_t* __restrict__ Wt,
    const float* __restrict__ bias, float* __restrict__ C,
    int M, int K, int Nc)
{
    __shared__ bf16_t As[128 * 72];
    int tid = threadIdx.x;
    int lane = tid & 63, w = tid >> 6;
    int wm = w >> 1, wn = w & 1;
    int lq = lane >> 4, lm = lane & 15;
    int m0 = blockIdx.y * 128, n0 = blockIdx.x * 64;

    f32x4 acc[4][2];
#pragma unroll
    for (int i = 0; i < 4; i++)
#pragma unroll
        for (int j = 0; j < 2; j++)
            acc[i][j] = (f32x4){0.f, 0.f, 0.f, 0.f};

    for (int k0 = 0; k0 < K; k0 += 64) {
#pragma unroll
        for (int i = 0; i < 4; i++) {
            int idx = tid + i * 256;
            int r = idx >> 3, c8 = idx & 7;
            int gm = m0 + r;
            bh8 v = {};
            if (gm < M) v = *(const bh8*)(A + (size_t)gm * K + k0 + c8 * 8);
            *(bh8*)(As + r * 72 + c8 * 8) = v;
        }
        __syncthreads();
#pragma unroll
        for (int kc = 0; kc < 2; kc++) {
            bh8 af[4], bf[2];
#pragma unroll
            for (int mt = 0; mt < 4; mt++)
                af[mt] = *(const bh8*)(As + (wm * 64 + mt * 16 + lm) * 72 + kc * 32 + lq * 8);
#pragma unroll
            for (int nt = 0; nt < 2; nt++)
                bf[nt] = *(const bh8*)(Wt + (size_t)(n0 + wn * 32 + nt * 16 + lm) * K + k0 + kc * 32 + lq * 8);
#pragma unroll
            for (int mt = 0; mt < 4; mt++)
#pragma unroll
                for (int nt = 0; nt < 2; nt++)
                    acc[mt][nt] = __builtin_amdgcn_mfma_f32_16x16x32_bf16(af[mt], bf[nt], acc[mt][nt], 0, 0, 0);
        }
        __syncthreads();
    }
#pragma unroll
    for (int nt = 0; nt < 2; nt++) {
        int gn = n0 + wn * 32 + nt * 16 + lm;
        if (gn >= Nc) continue;
        float bv = bias[gn];
#pragma unroll
        for (int mt = 0; mt < 4; mt++)
#pragma unroll
            for (int r = 0; r < 4; r++) {
                int gm = m0 + wm * 64 + mt * 16 + lq * 4 + r;
                if (gm < M) C[(size_t)gm * Nc + gn] = acc[mt][nt][r] + bv;
            }
    }
}

// ---------------- GATv2 aggregation: one WAVE per node, no LDS ----------------
// Buffers stride 256 (head stride 64; pad cols have attn=0). Two independent
// online-softmax chains (unroll-2) merged in-register.
// RES_INPLACE: P[n,f] += agg (P pre-written by GEMM: res0/identity).
// FINAL: out_final[n,0:40] += 0.25 * head-sum (out pre-written by eff GEMM).

template <int DVALID, bool FINAL, bool RES_INPLACE>
__global__ __launch_bounds__(256) void gat_agg_wave(
    const bf16_t* __restrict__ hs, const bf16_t* __restrict__ hd,
    const float* __restrict__ attn,
    const int* __restrict__ row_start, const int* __restrict__ src_sorted,
    bf16_t* __restrict__ P, float* __restrict__ out_final, int N)
{
    int w = threadIdx.x >> 6, l = threadIdx.x & 63;
    int n = blockIdx.x * 4 + w;
    if (n >= N) return;
    int h = l >> 4;
    int f0 = 4 * l;
    int dp = 4 * (l & 15);

    float at[4];
#pragma unroll
    for (int j = 0; j < 4; j++)
        at[j] = (dp + j < DVALID) ? attn[h * DVALID + dp + j] : 0.f;
    ushort4 hv = *(const ushort4*)(hd + (size_t)n * 256 + f0);
    float hdf[4] = { bf2f(hv.x), bf2f(hv.y), bf2f(hv.z), bf2f(hv.w) };

    int s = row_start[n], e = row_start[n + 1];

    float m0 = -INFINITY, ls0 = 0.f, a0[4] = {0.f, 0.f, 0.f, 0.f};
    float m1 = -INFINITY, ls1 = 0.f, a1[4] = {0.f, 0.f, 0.f, 0.f};

    int i = s;
    for (; i + 2 <= e; i += 2) {
        int sn0 = src_sorted[i];
        int sn1 = src_sorted[i + 1];
        ushort4 r0 = *(const ushort4*)(hs + (size_t)sn0 * 256 + f0);
        ushort4 r1 = *(const ushort4*)(hs + (size_t)sn1 * 256 + f0);
        float h0[4] = { bf2f(r0.x), bf2f(r0.y), bf2f(r0.z), bf2f(r0.w) };
        float h1[4] = { bf2f(r1.x), bf2f(r1.y), bf2f(r1.z), bf2f(r1.w) };
        float p0 = 0.f, p1 = 0.f;
#pragma unroll
        for (int j = 0; j < 4; j++) {
            float q0 = h0[j] + hdf[j], q1 = h1[j] + hdf[j];
            float lr0 = q0 > 0.f ? q0 : SLOPE * q0;
            float lr1 = q1 > 0.f ? q1 : SLOPE * q1;
            p0 += lr0 * at[j];
            p1 += lr1 * at[j];
        }
        p0 += __shfl_xor(p0, 1, 64); p1 += __shfl_xor(p1, 1, 64);
        p0 += __shfl_xor(p0, 2, 64); p1 += __shfl_xor(p1, 2, 64);
        p0 += __shfl_xor(p0, 4, 64); p1 += __shfl_xor(p1, 4, 64);
        p0 += __shfl_xor(p0, 8, 64); p1 += __shfl_xor(p1, 8, 64);
        if (p0 > m0) {
            float sc = __expf(m0 - p0);
            ls0 = ls0 * sc + 1.f;
#pragma unroll
            for (int j = 0; j < 4; j++) a0[j] = a0[j] * sc + h0[j];
            m0 = p0;
        } else {
            float p = __expf(p0 - m0);
            ls0 += p;
#pragma unroll
            for (int j = 0; j < 4; j++) a0[j] += p * h0[j];
        }
        if (p1 > m1) {
            float sc = __expf(m1 - p1);
            ls1 = ls1 * sc + 1.f;
#pragma unroll
            for (int j = 0; j < 4; j++) a1[j] = a1[j] * sc + h1[j];
            m1 = p1;
        } else {
            float p = __expf(p1 - m1);
            ls1 += p;
#pragma unroll
            for (int j = 0; j < 4; j++) a1[j] += p * h1[j];
        }
    }
    if (i < e) {   // tail edge -> chain 0
        int sn0 = src_sorted[i];
        ushort4 r0 = *(const ushort4*)(hs + (size_t)sn0 * 256 + f0);
        float h0[4] = { bf2f(r0.x), bf2f(r0.y), bf2f(r0.z), bf2f(r0.w) };
        float p0 = 0.f;
#pragma unroll
        for (int j = 0; j < 4; j++) {
            float q0 = h0[j] + hdf[j];
            float lr0 = q0 > 0.f ? q0 : SLOPE * q0;
            p0 += lr0 * at[j];
        }
        p0 += __shfl_xor(p0, 1, 64);
        p0 += __shfl_xor(p0, 2, 64);
        p0 += __shfl_xor(p0, 4, 64);
        p0 += __shfl_xor(p0, 8, 64);
        if (p0 > m0) {
            float sc = __expf(m0 - p0);
            ls0 = ls0 * sc + 1.f;
#pragma unroll
            for (int j = 0; j < 4; j++) a0[j] = a0[j] * sc + h0[j];
            m0 = p0;
        } else {
            float p = __expf(p0 - m0);
            ls0 += p;
#pragma unroll
            for (int j = 0; j < 4; j++) a0[j] += p * h0[j];
        }
    }

    float v[4] = {0.f, 0.f, 0.f, 0.f};
    if (e > s) {
        float M = fmaxf(m0, m1);
        float sc0 = __expf(m0 - M);          // chain1 empty -> m1=-inf -> sc1=0
        float sc1 = __expf(m1 - M);
        float inv = 1.f / (sc0 * ls0 + sc1 * ls1);
#pragma unroll
        for (int j = 0; j < 4; j++)
            v[j] = (sc0 * a0[j] + sc1 * a1[j]) * inv;
    }

    if (FINAL) {
        // head-sum: lanes l, l^16, l^32, l^48 hold the same d-range across heads
#pragma unroll
        for (int j = 0; j < 4; j++) {
            v[j] += __shfl_xor(v[j], 16, 64);
            v[j] += __shfl_xor(v[j], 32, 64);
        }
        if (l < DVALID / 4) {
            float4* op = (float4*)(out_final + (size_t)n * DVALID + 4 * l);
            float4 cur = *op;
            cur.x += 0.25f * v[0]; cur.y += 0.25f * v[1];
            cur.z += 0.25f * v[2]; cur.w += 0.25f * v[3];
            *op = cur;
        }
    } else {
        size_t oi = (size_t)n * 256 + f0;
        if (RES_INPLACE) {
            ushort4 pv = *(const ushort4*)(P + oi);
            v[0] += bf2f(pv.x); v[1] += bf2f(pv.y);
            v[2] += bf2f(pv.z); v[3] += bf2f(pv.w);
        }
        ushort4 ov = { f2bf(v[0]), f2bf(v[1]), f2bf(v[2]), f2bf(v[3]) };
        *(ushort4*)(P + oi) = ov;
    }
}

// ---------------- launch ----------------

extern "C" void kernel_launch(void* const* d_in, const int* in_sizes, int n_in,
                              void* d_out, int out_size, void* d_ws, size_t ws_size,
                              hipStream_t stream) {
    const float* x0    = (const float*)d_in[0];
    const int*   src   = (const int*)d_in[1];
    const int*   dst   = (const int*)d_in[2];
    const float* w_src0 = (const float*)d_in[3];  const float* b_src0 = (const float*)d_in[4];
    const float* w_dst0 = (const float*)d_in[5];  const float* b_dst0 = (const float*)d_in[6];
    const float* attn0  = (const float*)d_in[7];
    const float* w_res0 = (const float*)d_in[8];  const float* b_res0 = (const float*)d_in[9];
    const float* w_src1 = (const float*)d_in[10]; const float* b_src1 = (const float*)d_in[11];
    const float* w_dst1 = (const float*)d_in[12]; const float* b_dst1 = (const float*)d_in[13];
    const float* attn1  = (const float*)d_in[14];
    const float* w_src2 = (const float*)d_in[15]; const float* b_src2 = (const float*)d_in[16];
    const float* w_dst2 = (const float*)d_in[17]; const float* b_dst2 = (const float*)d_in[18];
    const float* attn2  = (const float*)d_in[19];
    const float* w_res2 = (const float*)d_in[20]; const float* b_res2 = (const float*)d_in[21];

    const int N = in_sizes[0] / 128;   // 50000
    const int E = in_sizes[1];         // 400000
    float* out = (float*)d_out;
    (void)n_in; (void)out_size; (void)ws_size;

    // ---- workspace (~79.7 MB) ----
    char* ws = (char*)d_ws;
    size_t off = 0;
    auto alloc = [&](size_t bytes) {
        void* q = ws + off;
        off = (off + bytes + 255) & ~(size_t)255;
        return q;
    };
    int* deg        = (int*)alloc((size_t)2 * N * 4);
    int* fill       = deg + N;
    int* row_start  = (int*)alloc((size_t)(N + 1) * 4);
    int* chunk_sums = (int*)alloc(256 * 4);
    int* src_sorted = (int*)alloc((size_t)E * 4);
    bf16_t* t_src0 = (bf16_t*)alloc(256 * 128 * 2);
    bf16_t* t_dst0 = (bf16_t*)alloc(256 * 128 * 2);
    bf16_t* t_res0 = (bf16_t*)alloc(256 * 128 * 2);
    bf16_t* t_src1 = (bf16_t*)alloc(256 * 256 * 2);
    bf16_t* t_dst1 = (bf16_t*)alloc(256 * 256 * 2);
    bf16_t* t_src2 = (bf16_t*)alloc(192 * 256 * 2);
    bf16_t* t_dst2 = (bf16_t*)alloc(192 * 256 * 2);
    bf16_t* t_eff  = (bf16_t*)alloc(64 * 256 * 2);
    float*  b_eff  = (float*)alloc(64 * 4);
    const size_t elems = (size_t)N * 256;
    bf16_t* P  = (bf16_t*)alloc(elems * 2);
    bf16_t* HS = (bf16_t*)alloc(elems * 2);
    bf16_t* HD = (bf16_t*)alloc(elems * 2);

    // ---- CSR build + weight conversion ----
    hipMemsetAsync(deg, 0, (size_t)2 * N * 4, stream);
    int eblocks = (E + 255) / 256;
    int nchunks = (N + 1023) / 1024;
    hipLaunchKernelGGL(hist_dst, dim3(eblocks), dim3(256), 0, stream, dst, E, deg);
    hipLaunchKernelGGL(convert_weights, dim3(1344), dim3(256), 0, stream,
                       w_src0, w_dst0, w_res0, w_src1, w_dst1, w_src2, w_dst2, w_res2, b_res2,
                       t_src0, t_dst0, t_res0, t_src1, t_dst1, t_src2, t_dst2, t_eff, b_eff);
    hipLaunchKernelGGL(deg_chunk_sum, dim3(nchunks), dim3(256), 0, stream, deg, N, chunk_sums);
    hipLaunchKernelGGL(scan_chunk_sums, dim3(1), dim3(256), 0, stream, chunk_sums, nchunks);
    hipLaunchKernelGGL(scan_write, dim3(nchunks), dim3(256), 0, stream, deg, N, chunk_sums, row_start, E);
    hipLaunchKernelGGL(scatter_edges, dim3(eblocks), dim3(256), 0, stream, dst, src, E, row_start, fill, src_sorted);

    dim3 blk(256);
    int mb = (N + 127) / 128;          // 391
    int ab = (N + 3) / 4;              // 12500 (wave-per-node agg)

    // ---- Layer 0: fused hs|hd|res from x0 (A staged once); agg adds onto res ----
    hipLaunchKernelGGL((gemm_fused<float, 3, false>), dim3(4, mb), blk, 0, stream,
                       x0, t_src0, t_dst0, t_res0, b_src0, b_dst0, b_res0,
                       HS, HD, P, N, 128, 256);
    hipLaunchKernelGGL((gat_agg_wave<64, false, true>), dim3(ab), blk, 0, stream,
                       HS, HD, attn0, row_start, src_sorted, P, (float*)nullptr, N);

    // ---- Layer 1: fused hs|hd from P; identity residual in-place ----
    hipLaunchKernelGGL((gemm_fused<bf16_t, 2, false>), dim3(4, mb), blk, 0, stream,
                       P, t_src1, t_dst1, (const bf16_t*)nullptr, b_src1, b_dst1, (const float*)nullptr,
                       HS, HD, (bf16_t*)nullptr, N, 256, 256);
    hipLaunchKernelGGL((gat_agg_wave<64, false, true>), dim3(ab), blk, 0, stream,
                       HS, HD, attn1, row_start, src_sorted, P, (float*)nullptr, N);

    // ---- Layer 2: fused hs|hd (SPLIT40); eff pre-writes out; FINAL agg accumulates ----
    hipLaunchKernelGGL((gemm_fused<bf16_t, 2, true>), dim3(3, mb), blk, 0, stream,
                       P, t_src2, t_dst2, (const bf16_t*)nullptr, b_src2, b_dst2, (const float*)nullptr,
                       HS, HD, (bf16_t*)nullptr, N, 256, 160);
    hipLaunchKernelGGL(gemm_eff, dim3(1, mb), blk, 0, stream,
                       P, t_eff, b_eff, out, N, 256, 40);
    hipLaunchKernelGGL((gat_agg_wave<40, true, false>), dim3(ab), blk, 0, stream,
                       HS, HD, attn2, row_start, src_sorted, (bf16_t*)nullptr, out, N);
}